// Round 5
// baseline (66.895 us; speedup 1.0000x reference)
//
#include <hip/hip_runtime.h>

// loss = sum_{i: yt=1, j: yt=0} max(0, 1 - yp_i + yp_j) / (n_pos * n_neg), N=16384.
//
// Round 5: R4 structure (one kernel, deterministic block-local LDS compaction,
// register-tiled pair phase) + two VALU squeezes:
//   - rows/block rounded to multiple of 4 (rpb4), cs sentinel-padded to
//     rpb4*GRID -> no per-row tail select; 4-row broadcast = 1 ds_read_b128.
//   - acc/qreg as adjacent float2 component pairs -> invite SLP into
//     v_pk_add_f32 / v_pk_max_f32 (packed fp32, gfx90a+) for 2x VALU rate.
// This is also a floor probe: harness re-poison fills (~39.5us, 85% HBM peak)
// + restores + replay gaps are ~60us of the 66.9; if dur doesn't move, we are
// at the harness floor.

#define N_TOTAL 16384
#define BLOCK 512
#define GRID 256
#define NWAVES (BLOCK / 64)
#define K_CHUNKS 8  // 8 x float4 per thread = 32 elems; 512*32 = 16384
#define SMEM_BYTES (2 * N_TOTAL * 4)

__global__ void __launch_bounds__(BLOCK) auc_kernel(
    const int* __restrict__ yt, const float* __restrict__ yp,
    float* __restrict__ out) {
  extern __shared__ float smem[];
  float* cs = smem;            // [16384] compacted 1-yp (pos) + sentinel pad
  float* qs = smem + N_TOTAL;  // [16384] compacted yp (neg) + sentinel pad
  __shared__ int waveTotS[NWAVES];
  __shared__ float wsum[NWAVES];

  const int tid = threadIdx.x;
  const int lane = tid & 63;
  const int wid = tid >> 6;
  const int b = blockIdx.x;

  // ---- pass 1: coalesced vector loads; values + pos-mask kept in registers
  float4 v[K_CHUNKS];
  unsigned mask = 0;
  int pc = 0;
#pragma unroll
  for (int k = 0; k < K_CHUNKS; ++k) {
    const int e = k * (BLOCK * 4) + tid * 4;
    const int4 t4 = *(const int4*)(yt + e);
    v[k] = *(const float4*)(yp + e);
    const unsigned m = (t4.x == 1 ? 1u : 0u) | (t4.y == 1 ? 2u : 0u) |
                       (t4.z == 1 ? 4u : 0u) | (t4.w == 1 ? 8u : 0u);
    mask |= m << (k * 4);
    pc += __popc(m);
  }

  // ---- wave pos-totals (butterfly), fixed-order prefix over waves
  int wtot = pc;
#pragma unroll
  for (int off = 1; off < 64; off <<= 1) wtot += __shfl_xor(wtot, off, 64);
  if (lane == 0) waveTotS[wid] = wtot;
  __syncthreads();
  int npos = 0, posBaseW = 0;
#pragma unroll
  for (int w = 0; w < NWAVES; ++w) {
    const int c = waveTotS[w];
    if (w < wid) posBaseW += c;
    npos += c;
  }
  const int nneg = N_TOTAL - npos;
  const int negBaseW = wid * 2048 - posBaseW;  // each wave owns 2048 elems

  // ---- pass 2: in-order per-wave ballot compaction (deterministic; stores
  //      rank-consecutive -> conflict-free; identical permutation all blocks)
  {
    int runP = 0, runN = 0;
    const unsigned long long lt = (1ull << lane) - 1ull;
#pragma unroll
    for (int k = 0; k < K_CHUNKS; ++k) {
#pragma unroll
      for (int c = 0; c < 4; ++c) {
        const float val = (c == 0) ? v[k].x
                        : (c == 1) ? v[k].y
                        : (c == 2) ? v[k].z : v[k].w;
        const bool isPos = (mask >> (k * 4 + c)) & 1u;
        const unsigned long long bal = __ballot(isPos);
        const int rankP = __popcll(bal & lt);
        if (isPos) cs[posBaseW + runP + rankP] = 1.0f - val;
        else       qs[negBaseW + runN + (lane - rankP)] = val;
        const int cnt = __popcll(bal);
        runP += cnt;
        runN += 64 - cnt;
      }
    }
  }

  // ---- sentinel pads; rpb4 multiple of 4 -> no per-row tail select later.
  // rpb4 <= 64 always, so rowsPad = rpb4*GRID <= 16384 fits cs[].
  const int rpb4 = (((npos + GRID - 1) / GRID) + 3) & ~3;
  const int rowsPad = rpb4 * GRID;
  for (int i = npos + tid; i < rowsPad; i += BLOCK) cs[i] = -3e30f;
  const int padded = (nneg + 3) & ~3;
  for (int i = nneg + tid; i < padded; i += BLOCK) qs[i] = -1e30f;
  __syncthreads();

  // ---- pair phase: rows [b*rpb4, (b+1)*rpb4), 16 q's/thread in registers,
  //      structured as float2 pairs for packed-f32 SLP.
  const int rowBase = b * rpb4;
  const int nCh = rpb4 >> 2;
  float accx[8], accy[8];
#pragma unroll
  for (int i = 0; i < 8; ++i) { accx[i] = 0.f; accy[i] = 0.f; }

  for (int jt = 0; jt < padded; jt += 8192) {
    if (jt + tid * 4 >= padded) break;  // tail threads idle (wave-coherent)
    float qx[8], qy[8];
#pragma unroll
    for (int w = 0; w < 4; ++w) {
      const int j0 = jt + w * 2048 + tid * 4;
      if (j0 < padded) {
        const float4 q4 = *(const float4*)(qs + j0);
        qx[w * 2 + 0] = q4.x; qy[w * 2 + 0] = q4.y;
        qx[w * 2 + 1] = q4.z; qy[w * 2 + 1] = q4.w;
      } else {
        qx[w * 2 + 0] = qy[w * 2 + 0] = -1e30f;
        qx[w * 2 + 1] = qy[w * 2 + 1] = -1e30f;
      }
    }
    for (int ch = 0; ch < nCh; ++ch) {
      // 4 consecutive rows, wave-uniform -> single ds_read_b128 broadcast.
      const float4 c4 = *(const float4*)(cs + rowBase + ch * 4);
      const float cv[4] = {c4.x, c4.y, c4.z, c4.w};
#pragma unroll
      for (int r = 0; r < 4; ++r) {
        const float cr = cv[r];
#pragma unroll
        for (int q = 0; q < 8; ++q) {
          accx[q] += fmaxf(0.f, cr + qx[q]);
          accy[q] += fmaxf(0.f, cr + qy[q]);
        }
      }
    }
  }

  // ---- reduce: thread -> wave -> block -> one atomicAdd per block
  float s = 0.f;
#pragma unroll
  for (int i = 0; i < 8; ++i) s += accx[i] + accy[i];
#pragma unroll
  for (int off = 32; off > 0; off >>= 1) s += __shfl_down(s, off, 64);
  if (lane == 0) wsum[wid] = s;
  __syncthreads();
  if (tid == 0) {
    float bs = 0.f;
#pragma unroll
    for (int w = 0; w < NWAVES; ++w) bs += wsum[w];
    atomicAdd(out, bs / ((float)npos * (float)nneg));
  }
}

extern "C" void kernel_launch(void* const* d_in, const int* in_sizes, int n_in,
                              void* d_out, int out_size, void* d_ws,
                              size_t ws_size, hipStream_t stream) {
  const int* yt = (const int*)d_in[0];      // y_true, int32, 16384
  const float* yp = (const float*)d_in[1];  // y_pred, float32, 16384
  float* out = (float*)d_out;

  // Opt in to 128KB dynamic LDS (host-side, capture-safe).
  hipFuncSetAttribute((const void*)auc_kernel,
                      hipFuncAttributeMaxDynamicSharedMemorySize, SMEM_BYTES);

  auc_kernel<<<GRID, BLOCK, SMEM_BYTES, stream>>>(yt, yp, out);
}